// Round 7
// baseline (65.246 us; speedup 1.0000x reference)
//
#include <hip/hip_runtime.h>
#include <float.h>

#define BT 8
#define NV 10000
#define NB 16384
#define NS 4096
#define NPTS (BT * NS)          // 32768 points
#define VCH 125                 // vertex chunks
#define CH 80                   // verts per chunk: 125*80 = 10000 exact, no tail
#define PB 8                    // point blocks = batches (4096 pts per block)

__device__ __forceinline__ float min3f(float a, float b, float c) {
    float d;
    asm("v_min3_f32 %0, %1, %2, %3" : "=v"(d) : "v"(a), "v"(b), "v"(c));
    return d;
}

// Stage 1: grid = PB * VCH = 1000 blocks (~4/CU). Block (b, c): all 4096 points
// of batch b vs verts [c*80, c*80+80). 16 points/thread; 80 verts staged in LDS.
__global__ void __launch_bounds__(256, 4)
stage1(const float* __restrict__ verts, const float4* __restrict__ bds4,
       const int* __restrict__ idx, float* __restrict__ pmin) {
    __shared__ float4 sv[CH];
    const int tid = threadIdx.x;
    const int b   = blockIdx.x & (PB - 1);     // batch
    const int c   = blockIdx.x >> 3;           // vertex chunk
    const int v0  = c * CH;

    // stage 80 verts as (-2x, -2y, -2z, |v|^2)
    if (tid < CH) {
        const float* vp = verts + (size_t)(b * NV + v0 + tid) * 3;
        float x = vp[0], y = vp[1], z = vp[2];
        sv[tid] = make_float4(-2.0f * x, -2.0f * y, -2.0f * z,
                              x * x + y * y + z * z);
    }

    float bx[16], by[16], bz[16], m[16];
#pragma unroll
    for (int k = 0; k < 16; ++k) {
        int s = tid + k * 256;                  // block covers whole batch
        float4 bp = bds4[(size_t)b * NB + idx[s]];
        bx[k] = bp.x; by[k] = bp.y; bz[k] = bp.z;
        m[k] = FLT_MAX;
    }
    __syncthreads();

    for (int v = 0; v < CH; v += 4) {
        float4 q0 = sv[v], q1 = sv[v + 1], q2 = sv[v + 2], q3 = sv[v + 3];
#pragma unroll
        for (int k = 0; k < 16; ++k) {
            float t0 = fmaf(bx[k], q0.x, fmaf(by[k], q0.y, fmaf(bz[k], q0.z, q0.w)));
            float t1 = fmaf(bx[k], q1.x, fmaf(by[k], q1.y, fmaf(bz[k], q1.z, q1.w)));
            float t2 = fmaf(bx[k], q2.x, fmaf(by[k], q2.y, fmaf(bz[k], q2.z, q2.w)));
            float t3 = fmaf(bx[k], q3.x, fmaf(by[k], q3.y, fmaf(bz[k], q3.z, q3.w)));
            m[k] = min3f(m[k], t0, t1);
            m[k] = min3f(m[k], t2, t3);
        }
    }

#pragma unroll
    for (int k = 0; k < 16; ++k)
        pmin[(size_t)c * NPTS + b * NS + tid + k * 256] = m[k];
}

// Stage 2: combine chunk mins, add sq_b, apply mask, per-block sum.
__global__ void stage2(const float* __restrict__ pmin, const float4* __restrict__ bds4,
                       const int* __restrict__ idx, float* __restrict__ bsum) {
    int pt = blockIdx.x * 256 + threadIdx.x;
    int b = pt >> 12, s = pt & (NS - 1);
    float4 bp = bds4[(size_t)b * NB + idx[s]];
    float md = FLT_MAX;
#pragma unroll 5
    for (int c = 0; c < VCH; ++c)
        md = fminf(md, pmin[(size_t)c * NPTS + pt]);
    float sqb = bp.x * bp.x + bp.y * bp.y + bp.z * bp.z;
    float val = (md + sqb) * bp.w * (1.0f / (float)NPTS);
    for (int o = 32; o > 0; o >>= 1) val += __shfl_down(val, o, 64);
    __shared__ float red[4];
    if ((threadIdx.x & 63) == 0) red[threadIdx.x >> 6] = val;
    __syncthreads();
    if (threadIdx.x == 0) bsum[blockIdx.x] = red[0] + red[1] + red[2] + red[3];
}

// Stage 3: final sum of 128 block partials -> scalar
__global__ void stage3(const float* __restrict__ bsum, float* __restrict__ out) {
    float v = bsum[threadIdx.x];  // 128 threads
    for (int o = 32; o > 0; o >>= 1) v += __shfl_down(v, o, 64);
    __shared__ float r[2];
    if ((threadIdx.x & 63) == 0) r[threadIdx.x >> 6] = v;
    __syncthreads();
    if (threadIdx.x == 0) out[0] = r[0] + r[1];
}

extern "C" void kernel_launch(void* const* d_in, const int* in_sizes, int n_in,
                              void* d_out, int out_size, void* d_ws, size_t ws_size,
                              hipStream_t stream) {
    const float*  verts = (const float*)d_in[0];
    const float4* bds4  = (const float4*)d_in[1];  // (BT, NB, 4) rows
    const int*    idx   = (const int*)d_in[3];     // int32
    float* out = (float*)d_out;

    char* ws = (char*)d_ws;
    float* pmin = (float*)ws;                                   // 125*32768*4 = 16 MB
    float* bsum = (float*)(ws + (size_t)VCH * NPTS * sizeof(float));  // 128 floats

    stage1<<<PB * VCH, 256, 0, stream>>>(verts, bds4, idx, pmin);
    stage2<<<NPTS / 256, 256, 0, stream>>>(pmin, bds4, idx, bsum);
    stage3<<<1, 128, 0, stream>>>(bsum, out);
}

// Round 8
// 62.793 us; speedup vs baseline: 1.0391x; 1.0391x over previous
//
#include <hip/hip_runtime.h>
#include <float.h>

#define BT 8
#define NV 10000
#define NB 16384
#define NS 4096
#define NPTS (BT * NS)          // 32768 points
#define PPT 8                   // points per thread (4 packed pairs)
#define PTSB (256 * PPT)        // 2048 points per block
#define PB (NPTS / PTSB)        // 16 point blocks
#define VCH 125                 // vertex chunks
#define CH 80                   // verts per chunk: 125*80 = 10000 exact

typedef float v2f __attribute__((ext_vector_type(2)));

// VOP3P packed fp32 FMA with op_sel broadcast of one 32-bit half of q.
// t = a * (q.z,q.z) + (q.w,q.w)   [innermost: z-term + |v|^2]
__device__ __forceinline__ v2f pk_fma_zw(v2f a, v2f q) {
    v2f d;
    asm("v_pk_fma_f32 %0, %1, %2, %2 op_sel:[0,0,1] op_sel_hi:[1,0,1]"
        : "=v"(d) : "v"(a), "v"(q));
    return d;
}
// t = a * (q.hi,q.hi) + c
__device__ __forceinline__ v2f pk_fma_hi(v2f a, v2f q, v2f c) {
    v2f d;
    asm("v_pk_fma_f32 %0, %1, %2, %3 op_sel:[0,1,0] op_sel_hi:[1,1,1]"
        : "=v"(d) : "v"(a), "v"(q), "v"(c));
    return d;
}
// t = a * (q.lo,q.lo) + c
__device__ __forceinline__ v2f pk_fma_lo(v2f a, v2f q, v2f c) {
    v2f d;
    asm("v_pk_fma_f32 %0, %1, %2, %3 op_sel:[0,0,0] op_sel_hi:[1,0,1]"
        : "=v"(d) : "v"(a), "v"(q), "v"(c));
    return d;
}
__device__ __forceinline__ float min3f(float a, float b, float c) {
    float d;
    asm("v_min3_f32 %0, %1, %2, %3" : "=v"(d) : "v"(a), "v"(b), "v"(c));
    return d;
}

// Stage 1: grid = PB * VCH = 2000 blocks (~8/CU). Block (pb, c): points
// [pb*2048, +2048) vs verts [c*80, +80). 8 pts/thread packed in float2 lanes;
// verts staged once in LDS as float4 (-2x,-2y,-2z,|v|^2) — 16 B each.
__global__ void __launch_bounds__(256, 4)
stage1(const float* __restrict__ verts, const float4* __restrict__ bds4,
       const int* __restrict__ idx, float* __restrict__ pmin) {
    __shared__ float4 sv[CH];
    const int tid = threadIdx.x;
    const int pb  = blockIdx.x % PB;
    const int c   = blockIdx.x / PB;
    const int b   = pb >> 1;            // 2 point-blocks per batch
    const int p0  = pb * PTSB;
    const int v0  = c * CH;

    if (tid < CH) {
        const float* vp = verts + (size_t)(b * NV + v0 + tid) * 3;
        float x = vp[0], y = vp[1], z = vp[2];
        sv[tid] = make_float4(-2.0f * x, -2.0f * y, -2.0f * z,
                              x * x + y * y + z * z);
    }

    v2f bx[4], by[4], bz[4];
    float mA[4], mB[4];
#pragma unroll
    for (int pp = 0; pp < 4; ++pp) {
        int pt0 = p0 + tid + pp * 512;
        int pt1 = pt0 + 256;
        float4 q0 = bds4[(size_t)b * NB + idx[pt0 & (NS - 1)]];
        float4 q1 = bds4[(size_t)b * NB + idx[pt1 & (NS - 1)]];
        bx[pp] = (v2f){q0.x, q1.x};
        by[pp] = (v2f){q0.y, q1.y};
        bz[pp] = (v2f){q0.z, q1.z};
        mA[pp] = FLT_MAX; mB[pp] = FLT_MAX;
    }
    __syncthreads();

    for (int v = 0; v < CH; v += 2) {
        float4 qa = sv[v], qb = sv[v + 1];
        v2f qa01 = {qa.x, qa.y}, qa23 = {qa.z, qa.w};
        v2f qb01 = {qb.x, qb.y}, qb23 = {qb.z, qb.w};
#pragma unroll
        for (int pp = 0; pp < 4; ++pp) {
            v2f t0 = pk_fma_zw(bz[pp], qa23);          // z*qa.z + qa.w
            t0 = pk_fma_hi(by[pp], qa01, t0);          // + y*qa.y
            t0 = pk_fma_lo(bx[pp], qa01, t0);          // + x*qa.x
            v2f t1 = pk_fma_zw(bz[pp], qb23);
            t1 = pk_fma_hi(by[pp], qb01, t1);
            t1 = pk_fma_lo(bx[pp], qb01, t1);
            mA[pp] = min3f(mA[pp], t0.x, t1.x);
            mB[pp] = min3f(mB[pp], t0.y, t1.y);
        }
    }

#pragma unroll
    for (int pp = 0; pp < 4; ++pp) {
        int pt0 = p0 + tid + pp * 512;
        pmin[(size_t)c * NPTS + pt0]       = mA[pp];
        pmin[(size_t)c * NPTS + pt0 + 256] = mB[pp];
    }
}

// Stage 2: combine chunk mins, add sq_b, apply mask, per-block sum.
__global__ void stage2(const float* __restrict__ pmin, const float4* __restrict__ bds4,
                       const int* __restrict__ idx, float* __restrict__ bsum) {
    int pt = blockIdx.x * 256 + threadIdx.x;
    int b = pt >> 12, s = pt & (NS - 1);
    float4 bp = bds4[(size_t)b * NB + idx[s]];
    float md = FLT_MAX;
#pragma unroll 5
    for (int c = 0; c < VCH; ++c)
        md = fminf(md, pmin[(size_t)c * NPTS + pt]);
    float sqb = bp.x * bp.x + bp.y * bp.y + bp.z * bp.z;
    float val = (md + sqb) * bp.w * (1.0f / (float)NPTS);
    for (int o = 32; o > 0; o >>= 1) val += __shfl_down(val, o, 64);
    __shared__ float red[4];
    if ((threadIdx.x & 63) == 0) red[threadIdx.x >> 6] = val;
    __syncthreads();
    if (threadIdx.x == 0) bsum[blockIdx.x] = red[0] + red[1] + red[2] + red[3];
}

// Stage 3: final sum of 128 block partials -> scalar
__global__ void stage3(const float* __restrict__ bsum, float* __restrict__ out) {
    float v = bsum[threadIdx.x];  // 128 threads
    for (int o = 32; o > 0; o >>= 1) v += __shfl_down(v, o, 64);
    __shared__ float r[2];
    if ((threadIdx.x & 63) == 0) r[threadIdx.x >> 6] = v;
    __syncthreads();
    if (threadIdx.x == 0) out[0] = r[0] + r[1];
}

extern "C" void kernel_launch(void* const* d_in, const int* in_sizes, int n_in,
                              void* d_out, int out_size, void* d_ws, size_t ws_size,
                              hipStream_t stream) {
    const float*  verts = (const float*)d_in[0];
    const float4* bds4  = (const float4*)d_in[1];  // (BT, NB, 4) rows
    const int*    idx   = (const int*)d_in[3];     // int32
    float* out = (float*)d_out;

    char* ws = (char*)d_ws;
    float* pmin = (float*)ws;                                         // 16 MB
    float* bsum = (float*)(ws + (size_t)VCH * NPTS * sizeof(float));  // 128 floats

    stage1<<<PB * VCH, 256, 0, stream>>>(verts, bds4, idx, pmin);
    stage2<<<NPTS / 256, 256, 0, stream>>>(pmin, bds4, idx, bsum);
    stage3<<<1, 128, 0, stream>>>(bsum, out);
}